// Round 4
// baseline (181.173 us; speedup 1.0000x reference)
//
#include <hip/hip_runtime.h>

static constexpr int B = 16, C = 64, H = 256, W = 256;
static constexpr int HW = H * W;              // 65536
static constexpr int KS = 7, PAD = 3;

typedef float f4 __attribute__((ext_vector_type(4)));
typedef unsigned short u16x4 __attribute__((ext_vector_type(4)));
typedef unsigned short u16x8 __attribute__((ext_vector_type(8)));

__device__ __forceinline__ unsigned short f2bf(float f) {   // RNE fp32->bf16
    unsigned u = __float_as_uint(f);
    return (unsigned short)((u + 0x7FFFu + ((u >> 16) & 1u)) >> 16);
}

// ---- K1 (stash path): mean/max + bf16 stash of x -------------------------
// x read with NT loads (no L3 allocate -> don't evict the stash).
// Stash stores are regular: 134 MB < 256 MB L3, stays resident for K3, and
// in graph-replay steady state the lines are re-dirtied in place (no HBM wb).
__global__ void __launch_bounds__(256) reduce_stash(
    const float* __restrict__ x, float* __restrict__ avg, float* __restrict__ mx,
    unsigned short* __restrict__ xh)
{
    int idx = blockIdx.x * 256 + threadIdx.x;     // over B*HW/4
    int b   = idx >> 14;                          // HW/4 = 2^14
    int p   = idx & (HW / 4 - 1);
    const f4* xp = reinterpret_cast<const f4*>(x) + (size_t)b * (C * (HW / 4)) + p;
    u16x4*    hp = reinterpret_cast<u16x4*>(xh)   + (size_t)b * (C * (HW / 4)) + p;
    f4 s = {0.f, 0.f, 0.f, 0.f};
    f4 a = {-INFINITY, -INFINITY, -INFINITY, -INFINITY};
    #pragma unroll 8
    for (int c = 0; c < C; ++c) {
        f4 t = __builtin_nontemporal_load(xp + (size_t)c * (HW / 4));
        s += t;
        a.x = fmaxf(a.x, t.x); a.y = fmaxf(a.y, t.y);
        a.z = fmaxf(a.z, t.z); a.w = fmaxf(a.w, t.w);
        u16x4 h;
        h.x = f2bf(t.x); h.y = f2bf(t.y); h.z = f2bf(t.z); h.w = f2bf(t.w);
        hp[(size_t)c * (HW / 4)] = h;
    }
    const float inv = 1.0f / C;
    size_t o = (size_t)b * (HW / 4) + p;
    reinterpret_cast<f4*>(avg)[o] = s * inv;
    reinterpret_cast<f4*>(mx)[o]  = a;
}

// ---- K1 (fallback, no stash): round-2 kernel -----------------------------
__global__ void __launch_bounds__(256) reduce_mean_max(
    const float* __restrict__ x, float* __restrict__ avg, float* __restrict__ mx)
{
    int idx = blockIdx.x * 256 + threadIdx.x;
    int b   = idx >> 14;
    const f4* xp = reinterpret_cast<const f4*>(x)
                 + (size_t)b * (C * (HW / 4)) + (idx & (HW / 4 - 1));
    f4 v = xp[0];
    f4 s = v, a = v;
    #pragma unroll 8
    for (int c = 1; c < C; ++c) {
        f4 t = xp[(size_t)c * (HW / 4)];
        s += t;
        a.x = fmaxf(a.x, t.x); a.y = fmaxf(a.y, t.y);
        a.z = fmaxf(a.z, t.z); a.w = fmaxf(a.w, t.w);
    }
    const float inv = 1.0f / C;
    reinterpret_cast<f4*>(avg)[idx] = s * inv;
    reinterpret_cast<f4*>(mx)[idx]  = a;
}

// ---- K2: 7x7 conv (2->1) + bias + sigmoid --------------------------------
__global__ void __launch_bounds__(256) conv_sigmoid(
    const float* __restrict__ avg, const float* __restrict__ mx,
    const float* __restrict__ wgt, const float* __restrict__ bias,
    float* __restrict__ mask)
{
    constexpr int TS = 16;
    constexpr int TI = TS + KS - 1;   // 22
    __shared__ float sa[TI][24];
    __shared__ float sm[TI][24];

    const int tx = threadIdx.x & 15;
    const int ty = threadIdx.x >> 4;
    const int w0 = blockIdx.x * TS;
    const int h0 = blockIdx.y * TS;
    const int b  = blockIdx.z;

    const float* ap = avg + (size_t)b * HW;
    const float* mp = mx  + (size_t)b * HW;

    for (int e = threadIdx.x; e < TI * TI; e += 256) {
        int r = e / TI, c = e % TI;
        int gh = h0 + r - PAD, gw = w0 + c - PAD;
        bool ok = ((unsigned)gh < (unsigned)H) && ((unsigned)gw < (unsigned)W);
        int gi = gh * W + gw;
        sa[r][c] = ok ? ap[gi] : 0.0f;
        sm[r][c] = ok ? mp[gi] : 0.0f;
    }
    __syncthreads();

    float acc = bias[0];
    #pragma unroll
    for (int ky = 0; ky < KS; ++ky) {
        #pragma unroll
        for (int kx = 0; kx < KS; ++kx) {
            acc += sa[ty + ky][tx + kx] * wgt[ky * KS + kx];
            acc += sm[ty + ky][tx + kx] * wgt[49 + ky * KS + kx];
        }
    }
    float s = 1.0f / (1.0f + expf(-acc));
    mask[(size_t)b * HW + (h0 + ty) * W + (w0 + tx)] = s;
}

// ---- K3 (stash path): out = bf16(x) * mask, stash read from L3 -----------
__global__ void __launch_bounds__(256) apply_stash(
    const unsigned short* __restrict__ xh, const float* __restrict__ mask,
    float* __restrict__ out)
{
    int idx = blockIdx.x * 256 + threadIdx.x;     // over B*C*HW/8
    int b   = idx >> 19;                          // C*HW/8 = 2^19
    int hw8 = idx & (HW / 8 - 1);
    u16x8 hv = reinterpret_cast<const u16x8*>(xh)[idx];
    const f4* mp = reinterpret_cast<const f4*>(mask) + ((size_t)b << 14) + 2 * hw8;
    f4 m0 = mp[0], m1 = mp[1];
    f4 x0, x1;
    x0.x = __uint_as_float((unsigned)hv[0] << 16);
    x0.y = __uint_as_float((unsigned)hv[1] << 16);
    x0.z = __uint_as_float((unsigned)hv[2] << 16);
    x0.w = __uint_as_float((unsigned)hv[3] << 16);
    x1.x = __uint_as_float((unsigned)hv[4] << 16);
    x1.y = __uint_as_float((unsigned)hv[5] << 16);
    x1.z = __uint_as_float((unsigned)hv[6] << 16);
    x1.w = __uint_as_float((unsigned)hv[7] << 16);
    f4* op = reinterpret_cast<f4*>(out) + 2 * (size_t)idx;
    __builtin_nontemporal_store(x0 * m0, op);
    __builtin_nontemporal_store(x1 * m1, op + 1);
}

// ---- K3 (fallback): re-read fp32 x ---------------------------------------
__global__ void __launch_bounds__(256) apply_mask(
    const float* __restrict__ x, const float* __restrict__ mask,
    float* __restrict__ out)
{
    int idx = blockIdx.x * 256 + threadIdx.x;
    int b   = idx >> 20;
    int hw4 = idx & (HW / 4 - 1);
    f4 xv = reinterpret_cast<const f4*>(x)[idx];
    f4 mv = reinterpret_cast<const f4*>(mask)[(b << 14) + hw4];
    __builtin_nontemporal_store(xv * mv, reinterpret_cast<f4*>(out) + idx);
}

extern "C" void kernel_launch(void* const* d_in, const int* in_sizes, int n_in,
                              void* d_out, int out_size, void* d_ws, size_t ws_size,
                              hipStream_t stream) {
    const float* x      = (const float*)d_in[0];
    const float* conv_w = (const float*)d_in[1];   // [1,2,7,7] OIHW flat
    const float* conv_b = (const float*)d_in[2];   // [1]
    float* out  = (float*)d_out;

    float* avg  = (float*)d_ws;                          // 4 MiB
    float* mx   = avg + (size_t)B * HW;                  // 4 MiB
    float* mask = mx  + (size_t)B * HW;                  // 4 MiB
    unsigned short* xh = (unsigned short*)(mask + (size_t)B * HW); // 128 MiB

    const size_t need = (size_t)3 * B * HW * sizeof(float)
                      + (size_t)B * C * HW * sizeof(unsigned short);
    const bool stash = ws_size >= need;

    if (stash)
        reduce_stash<<<(B * HW / 4) / 256, 256, 0, stream>>>(x, avg, mx, xh);
    else
        reduce_mean_max<<<(B * HW / 4) / 256, 256, 0, stream>>>(x, avg, mx);

    dim3 cgrid(W / 16, H / 16, B);
    conv_sigmoid<<<cgrid, 256, 0, stream>>>(avg, mx, conv_w, conv_b, mask);

    if (stash)
        apply_stash<<<(B * C * HW / 8) / 256, 256, 0, stream>>>(xh, mask, out);
    else
        apply_mask<<<(B * C * HW / 4) / 256, 256, 0, stream>>>(x, mask, out);
}

// Round 5
// 144.586 us; speedup vs baseline: 1.2530x; 1.2530x over previous
//
#include <hip/hip_runtime.h>

static constexpr int B = 16, C = 64, H = 256, W = 256;
static constexpr int HW = H * W;              // 65536
static constexpr int KS = 7, PAD = 3;

typedef float f4 __attribute__((ext_vector_type(4)));

// ---------------- Kernel 1: channel-wise mean & max ----------------
// Thread = one pixel-quad (f4), loops over 64 channels (stride HW), fully
// coalesced 1 KiB/wave/instr. Ascending scan; regular loads so x populates
// L3 with recency = address order (tail resident at kernel end).
__global__ void __launch_bounds__(256) reduce_mean_max(
    const float* __restrict__ x, float* __restrict__ avg, float* __restrict__ mx)
{
    int idx = blockIdx.x * 256 + threadIdx.x;     // over B*HW/4 = 262144
    int b   = idx >> 14;                          // HW/4 = 16384 = 2^14
    const f4* xp = reinterpret_cast<const f4*>(x)
                 + (size_t)b * (C * (HW / 4)) + (idx & (HW / 4 - 1));
    f4 v = xp[0];
    f4 s = v, a = v;
    #pragma unroll 8
    for (int c = 1; c < C; ++c) {
        f4 t = xp[(size_t)c * (HW / 4)];
        s += t;
        a.x = fmaxf(a.x, t.x); a.y = fmaxf(a.y, t.y);
        a.z = fmaxf(a.z, t.z); a.w = fmaxf(a.w, t.w);
    }
    const float inv = 1.0f / C;
    reinterpret_cast<f4*>(avg)[idx] = s * inv;
    reinterpret_cast<f4*>(mx)[idx]  = a;
}

// ---------------- Kernel 2: 7x7 conv (2->1) + bias + sigmoid ----------------
// 16x16 output tile per 256-thread block; 22x22 halo staged in LDS with
// row stride 24 (2-way bank aliasing only -> free).
__global__ void __launch_bounds__(256) conv_sigmoid(
    const float* __restrict__ avg, const float* __restrict__ mx,
    const float* __restrict__ wgt, const float* __restrict__ bias,
    float* __restrict__ mask)
{
    constexpr int TS = 16;
    constexpr int TI = TS + KS - 1;   // 22
    __shared__ float sa[TI][24];
    __shared__ float sm[TI][24];

    const int tx = threadIdx.x & 15;
    const int ty = threadIdx.x >> 4;
    const int w0 = blockIdx.x * TS;
    const int h0 = blockIdx.y * TS;
    const int b  = blockIdx.z;

    const float* ap = avg + (size_t)b * HW;
    const float* mp = mx  + (size_t)b * HW;

    for (int e = threadIdx.x; e < TI * TI; e += 256) {
        int r = e / TI, c = e % TI;
        int gh = h0 + r - PAD, gw = w0 + c - PAD;
        bool ok = ((unsigned)gh < (unsigned)H) && ((unsigned)gw < (unsigned)W);
        int gi = gh * W + gw;
        sa[r][c] = ok ? ap[gi] : 0.0f;
        sm[r][c] = ok ? mp[gi] : 0.0f;
    }
    __syncthreads();

    float acc = bias[0];
    #pragma unroll
    for (int ky = 0; ky < KS; ++ky) {
        #pragma unroll
        for (int kx = 0; kx < KS; ++kx) {
            acc += sa[ty + ky][tx + kx] * wgt[ky * KS + kx];
            acc += sm[ty + ky][tx + kx] * wgt[49 + ky * KS + kx];
        }
    }
    float s = 1.0f / (1.0f + expf(-acc));
    mask[(size_t)b * HW + (h0 + ty) * W + (w0 + tx)] = s;
}

// ---------------- Kernel 3: out = x * mask, REVERSED scan ----------------
// Same layout as kernel 1 (thread = pixel-quad, c-loop) so the mask value
// is loaded once into a register and reused for all 64 channels.
// Block order REVERSED: consume k1's L3-resident tail first (ping-pong
// scan direction defeats the LRU cyclic-thrash of a 268 MB stream vs the
// 256 MB Infinity Cache). out stores are non-temporal: never re-read,
// must not evict x.
__global__ void __launch_bounds__(256) apply_mask_rev(
    const float* __restrict__ x, const float* __restrict__ mask,
    float* __restrict__ out)
{
    int bid = (int)gridDim.x - 1 - (int)blockIdx.x;   // descending scan
    int idx = bid * 256 + threadIdx.x;                // over B*HW/4
    int b   = idx >> 14;
    int p   = idx & (HW / 4 - 1);
    f4 mv = reinterpret_cast<const f4*>(mask)[idx];
    size_t base = (size_t)b * (C * (HW / 4)) + p;
    const f4* xp = reinterpret_cast<const f4*>(x)   + base;
    f4*       op = reinterpret_cast<f4*>(out)       + base;
    #pragma unroll 8
    for (int c = 0; c < C; ++c) {
        f4 xv = xp[(size_t)c * (HW / 4)];
        __builtin_nontemporal_store(xv * mv, op + (size_t)c * (HW / 4));
    }
}

extern "C" void kernel_launch(void* const* d_in, const int* in_sizes, int n_in,
                              void* d_out, int out_size, void* d_ws, size_t ws_size,
                              hipStream_t stream) {
    const float* x      = (const float*)d_in[0];
    const float* conv_w = (const float*)d_in[1];   // [1,2,7,7] OIHW flat
    const float* conv_b = (const float*)d_in[2];   // [1]
    float* out  = (float*)d_out;

    float* avg  = (float*)d_ws;                    // B*HW floats = 4 MiB
    float* mx   = avg + (size_t)B * HW;            // 4 MiB
    float* mask = mx  + (size_t)B * HW;            // 4 MiB

    reduce_mean_max<<<(B * HW / 4) / 256, 256, 0, stream>>>(x, avg, mx);

    dim3 cgrid(W / 16, H / 16, B);
    conv_sigmoid<<<cgrid, 256, 0, stream>>>(avg, mx, conv_w, conv_b, mask);

    apply_mask_rev<<<(B * HW / 4) / 256, 256, 0, stream>>>(x, mask, out);
}